// Round 1
// baseline (121.536 us; speedup 1.0000x reference)
//
#include <hip/hip_runtime.h>
#include <hip/hip_fp16.h>

#define BATCH 16
#define H 512
#define W 512
#define BH 128
#define BW 128
#define HG 510   // interior rows (buffer rows 0..509 <-> pixel rows 1..510)
#define WG 510

// pack: (mag_bits & ~31) | o  -- o in [0,18) fits 5 bits; mag rel err ~3e-6
// o is chosen BEFORE truncation, so argmax decisions are bit-identical to ref.

// ---------------- Fused kernel 1+2: gradient+orientation -> LDS -> cell histograms ----
// R8: pk intermediate never touches HBM. Per block: 16x16 cells (64x64 px).
// Phase 1 computes packed grad/orientation for the 68x69 halo region into LDS
// (18 quads x 68 rows, 5 iters of 256 threads). Out-of-range px stored as 0 ->
// every boundary contribution is an exact +0.0 (same result as k2's
// weight-zeroing; fp16 adds of +0 are exact no-ops on non-negative bins).
// Phase 2 == old k2 inner loop, reading L/M/X from LDS. Accumulation order and
// weight values preserved bit-for-bit vs the 116us version.
// LDS: pk 68*72*4 = 19584 B + 2 hist bufs 18432 B = 38016 B -> 4 blocks/CU.
__global__ __launch_bounds__(256, 4) void hog_gradhist(const float* __restrict__ img,
                                                       __half2* __restrict__ hist,
                                                       float* __restrict__ nrm)
{
    __shared__ unsigned int pk[68 * 72];
    __shared__ __half2 hl0[9 * 256];
    __shared__ __half2 hl1[9 * 256];

    const int t = threadIdx.x;
    const int b = blockIdx.z;
    const int cx0 = blockIdx.x * 16;   // tile cell origin
    const int cy0 = blockIdx.y * 16;
    const int gr0 = 4 * cy0 - 3;       // pk row of LDS row 0
    const int gc0 = 4 * cx0 - 4;       // pk col of LDS col 0

    const float* im = img + (size_t)b * 3 * H * W;

    const float uu[9] = {1.0f, 0.9397f, 0.766f, 0.5f, 0.1736f, -0.1736f, -0.5f, -0.766f, -0.9397f};
    const float vv[9] = {0.0f, 0.342f, 0.6428f, 0.866f, 0.9848f, 0.9848f, 0.866f, 0.6428f, 0.342f};

    const __half2 z2 = __halves2half2(__ushort_as_half(0), __ushort_as_half(0));
#pragma unroll
    for (int o = 0; o < 9; o++) { hl0[o * 256 + t] = z2; hl1[o * 256 + t] = z2; }
    // hl columns are per-thread private (index t) -> no barrier needed for them

    // ---- phase 1: 68 rows x 18 quads = 1224 quads, 5 sweeps ----
    for (int it = 0; it < 5; ++it) {
        int s = it * 256 + t;
        if (s >= 68 * 18) break;
        int r = s / 18;
        int q = s - r * 18;
        int gr = gr0 + r;            // pk row of this quad
        int gc = gc0 + 4 * q;        // pk col of px 0 (multiple of 4)
        unsigned int pkv[4] = {0u, 0u, 0u, 0u};
        if (gr >= 0 && gr < HG && gc >= 0 && gc < WG) {
            // valid quads have gc in {0,4,...,508}; image rows gr..gr+2 <= 511 in-bounds.
            // f2 tail at gc+4 would hit col 512 only when gc==508: clamp to 510;
            // the displaced values feed only px cols 510/511 which are masked to 0.
            int o2 = (gc == 508) ? 2 : 4;
            float bv[4] = {-1.f, -1.f, -1.f, -1.f}, bxv[4], byv[4];
            const float* p0 = im + (size_t)gr * W + gc;
#pragma unroll
            for (int c = 0; c < 3; c++) {
                const float* pu = p0 + (size_t)c * H * W;  // image row gr   (y-1)
                const float* pm = pu + W;                  // image row gr+1 (y)
                const float* pd = pm + W;                  // image row gr+2 (y+1)
                float4 a0 = *(const float4*)pu;  float2 e0 = *(const float2*)(pu + o2);
                float4 a1 = *(const float4*)pm;  float2 e1 = *(const float2*)(pm + o2);
                float4 a2 = *(const float4*)pd;  float2 e2 = *(const float2*)(pd + o2);
                float u_[6] = {a0.x, a0.y, a0.z, a0.w, e0.x, e0.y};
                float m_[6] = {a1.x, a1.y, a1.z, a1.w, e1.x, e1.y};
                float d_[6] = {a2.x, a2.y, a2.z, a2.w, e2.x, e2.y};
#pragma unroll
                for (int i = 0; i < 4; i++) {
                    float dx = __fsub_rn(m_[i + 2], m_[i]);
                    float dy = __fsub_rn(d_[i + 1], u_[i + 1]);
                    float v = __fadd_rn(__fmul_rn(dx, dx), __fmul_rn(dy, dy));
                    if (v > bv[i]) { bv[i] = v; bxv[i] = dx; byv[i] = dy; }
                }
            }
#pragma unroll
            for (int i = 0; i < 4; i++) {
                if (gc + i < WG) {
                    float mg = __fsqrt_rn(bv[i]);
                    float dt[9];
#pragma unroll
                    for (int o = 0; o < 9; o++)
                        dt[o] = __fadd_rn(__fmul_rn(uu[o], bxv[i]), __fmul_rn(vv[o], byv[i]));
                    float best = -1e30f; int bo = 0;
#pragma unroll
                    for (int o = 0; o < 9; o++) { if (dt[o] > best) { best = dt[o]; bo = o; } }
#pragma unroll
                    for (int o = 0; o < 9; o++) { float nd = -dt[o]; if (nd > best) { best = nd; bo = o + 9; } }
                    pkv[i] = (__float_as_uint(mg) & 0xFFFFFFE0u) | (unsigned int)bo;
                }
            }
        }
        *(uint4*)&pk[r * 72 + 4 * q] = make_uint4(pkv[0], pkv[1], pkv[2], pkv[3]);
    }

    __syncthreads();

    // ---- phase 2: old k2 gather, sources from LDS ----
    const int cxL = t & 15, cyL = t >> 4;
    const float wt8[8] = {0.125f, 0.375f, 0.625f, 0.875f, 0.875f, 0.625f, 0.375f, 0.125f};

#define ACC(B, P, WW) { unsigned _p = (P); unsigned _o = _p & 31u;                         \
        __half _hv = __float2half((WW) * __uint_as_float(_p & 0xFFFFFFE0u));               \
        bool _lo = _o < 9u; unsigned _o9 = _lo ? _o : _o - 9u;                             \
        __half2 _ad = _lo ? __halves2half2(_hv, __ushort_as_half(0))                       \
                          : __halves2half2(__ushort_as_half(0), _hv);                      \
        B[_o9 * 256 + t] = __hadd2(B[_o9 * 256 + t], _ad); }

#pragma unroll
    for (int ky = 0; ky < 8; ky++) {
        const unsigned int* row = &pk[(4 * cyL + ky) * 72];
        uint4 L = *(const uint4*)&row[4 * cxL];       // pk cols 4cx-4..-1 (halo/zero)
        uint4 M = *(const uint4*)&row[4 * cxL + 4];   // pk cols 4cx..4cx+3
        unsigned int X = row[4 * cxL + 8];            // pk col 4cx+4 (halo/zero)
        float wy = wt8[ky];
        ACC(hl0, L.y, wy * 0.125f);
        ACC(hl1, L.z, wy * 0.375f);
        ACC(hl0, L.w, wy * 0.625f);
        ACC(hl1, M.x, wy * 0.875f);
        ACC(hl0, M.y, wy * 0.875f);
        ACC(hl1, M.z, wy * 0.625f);
        ACC(hl0, M.w, wy * 0.375f);
        ACC(hl1, X,   wy * 0.125f);
    }
#undef ACC

    const int cx = cx0 + cxL, cy = cy0 + cyL;
    float s = 0.0f;
#pragma unroll
    for (int o = 0; o < 9; o++) {
        __half2 hh = __hadd2(hl0[o * 256 + t], hl1[o * 256 + t]);
        hist[(((size_t)b * 9 + o) * BH + cy) * BW + cx] = hh;
        float2 f = __half22float2(hh);
        float ss = f.x + f.y;
        s += ss * ss;
    }
    nrm[((size_t)b * BH + cy) * BW + cx] = s;
}

// ---------------- Kernel 3: normalization + features, 4 cells/thread ----------------
__global__ __launch_bounds__(256) void hog_feat(const __half2* __restrict__ hist,
                                                const float* __restrict__ nrm,
                                                float* __restrict__ out)
{
    int tx = threadIdx.x;                   // 0..31 (x-quad)
    int oy = blockIdx.y * 8 + threadIdx.y;  // 0..127
    int b  = blockIdx.z;
    int cx0 = tx * 4;

    if (oy == 0 || oy == BH - 1) {
        float4 z4 = make_float4(0.f, 0.f, 0.f, 0.f);
#pragma unroll
        for (int c = 0; c < 31; c++)
            *(float4*)(out + (((size_t)b * 31 + c) * BH + oy) * BW + cx0) = z4;
        return;
    }

    float v1[4], v2[4], v3[4], v4[4];
    {
        const float* nb = nrm + (size_t)b * BH * BW;
        float nn[3][6];
#pragma unroll
        for (int r = 0; r < 3; r++) {
            const float* rp = nb + (size_t)(oy - 1 + r) * BW + cx0;
#pragma unroll
            for (int j = 0; j < 6; j++) nn[r][j] = rp[j - 1];
        }
#pragma unroll
        for (int i = 0; i < 4; i++) {
            float T11 = nn[1][i+1] + nn[2][i+1] + nn[1][i+2] + nn[2][i+2];
            float T01 = nn[0][i+1] + nn[1][i+1] + nn[0][i+2] + nn[1][i+2];
            float T10 = nn[1][i]   + nn[2][i]   + nn[1][i+1] + nn[2][i+1];
            float T00 = nn[0][i]   + nn[1][i]   + nn[0][i+1] + nn[1][i+1];
            v1[i] = 1.0f / __fsqrt_rn(T11 + 1e-4f);
            v2[i] = 1.0f / __fsqrt_rn(T01 + 1e-4f);
            v3[i] = 1.0f / __fsqrt_rn(T10 + 1e-4f);
            v4[i] = 1.0f / __fsqrt_rn(T00 + 1e-4f);
        }
    }

    float h[4][18];
#pragma unroll
    for (int o = 0; o < 9; o++) {
        uint4 q = *(const uint4*)(hist + (((size_t)b * 9 + o) * BH + oy) * BW + cx0);
        unsigned vs[4] = {q.x, q.y, q.z, q.w};
#pragma unroll
        for (int i = 0; i < 4; i++) {
            float2 f = __half22float2(*(__half2*)&vs[i]);
            h[i][o] = f.x; h[i][o + 9] = f.y;
        }
    }

    bool msk[4];
#pragma unroll
    for (int i = 0; i < 4; i++) { int cxi = cx0 + i; msk[i] = (cxi >= 1 && cxi <= 126); }

    float t1[4] = {0,0,0,0}, t2[4] = {0,0,0,0}, t3[4] = {0,0,0,0}, t4[4] = {0,0,0,0};
    float* ob = out + ((size_t)b * 31) * BH * BW + (size_t)oy * BW + cx0;

#pragma unroll
    for (int o = 0; o < 18; o++) {
        float st[4];
#pragma unroll
        for (int i = 0; i < 4; i++) {
            float s = h[i][o];
            float a1 = fminf(s * v1[i], 0.2f);
            float a2 = fminf(s * v2[i], 0.2f);
            float a3 = fminf(s * v3[i], 0.2f);
            float a4 = fminf(s * v4[i], 0.2f);
            t1[i] += a1; t2[i] += a2; t3[i] += a3; t4[i] += a4;
            st[i] = msk[i] ? 0.5f * (a1 + a2 + a3 + a4) : 0.f;
        }
        *(float4*)(ob + (size_t)o * BH * BW) = make_float4(st[0], st[1], st[2], st[3]);
    }
#pragma unroll
    for (int o = 0; o < 9; o++) {
        float st[4];
#pragma unroll
        for (int i = 0; i < 4; i++) {
            float ss = h[i][o] + h[i][o + 9];
            float a1 = fminf(ss * v1[i], 0.2f);
            float a2 = fminf(ss * v2[i], 0.2f);
            float a3 = fminf(ss * v3[i], 0.2f);
            float a4 = fminf(ss * v4[i], 0.2f);
            st[i] = msk[i] ? 0.5f * (a1 + a2 + a3 + a4) : 0.f;
        }
        *(float4*)(ob + (size_t)(18 + o) * BH * BW) = make_float4(st[0], st[1], st[2], st[3]);
    }
    {
        float s1[4], s2[4], s3[4], s4[4];
#pragma unroll
        for (int i = 0; i < 4; i++) {
            s1[i] = msk[i] ? 0.2357f * t1[i] : 0.f;
            s2[i] = msk[i] ? 0.2357f * t2[i] : 0.f;
            s3[i] = msk[i] ? 0.2357f * t3[i] : 0.f;
            s4[i] = msk[i] ? 0.2357f * t4[i] : 0.f;
        }
        *(float4*)(ob + (size_t)27 * BH * BW) = make_float4(s1[0], s1[1], s1[2], s1[3]);
        *(float4*)(ob + (size_t)28 * BH * BW) = make_float4(s2[0], s2[1], s2[2], s2[3]);
        *(float4*)(ob + (size_t)29 * BH * BW) = make_float4(s3[0], s3[1], s3[2], s3[3]);
        *(float4*)(ob + (size_t)30 * BH * BW) = make_float4(s4[0], s4[1], s4[2], s4[3]);
    }
}

extern "C" void kernel_launch(void* const* d_in, const int* in_sizes, int n_in,
                              void* d_out, int out_size, void* d_ws, size_t ws_size,
                              hipStream_t stream)
{
    const float* img = (const float*)d_in[0];
    float* out = (float*)d_out;
    char* ws = (char*)d_ws;

    // workspace layout:
    //   hist : 16*9*128*128*4 = 9,437,184 @ 0   (half2-packed bins o|o+9)
    //   nrm  : 16*128*128*4   = 1,048,576 @ 9,437,184   (end 10,485,760)
    __half2* hist = (__half2*)ws;
    float* nrm    = (float*)(ws + 9437184);

    dim3 b1(256, 1, 1), g1(BW / 16, BH / 16, BATCH);
    hog_gradhist<<<g1, b1, 0, stream>>>(img, hist, nrm);

    dim3 b3(32, 8, 1), g3(1, BH / 8, BATCH);
    hog_feat<<<g3, b3, 0, stream>>>(hist, nrm, out);
}